// Round 16
// baseline (774.164 us; speedup 1.0000x reference)
//
#include <hip/hip_runtime.h>
#include <math.h>

using u16 = unsigned short;
using u32 = unsigned int;
typedef __attribute__((ext_vector_type(8))) short bf16x8;
typedef __attribute__((ext_vector_type(4))) float f32x4;
typedef __attribute__((ext_vector_type(16))) float f32x16;

#define NPLANE 65536
#define BELEMS ((size_t)6291456)     /* 96*65536 elements per batch */
#define ASTR   ((size_t)33423360)    /* bufA batch stride: 510*65536 u16 */
#define BSTR   ((size_t)18874368)    /* bufB batch stride: 288*65536 u16 */

__device__ __forceinline__ float bf2f(u16 u) { return __uint_as_float(((u32)u) << 16); }
__device__ __forceinline__ u16 f2bf(float f) {
  if (!__builtin_isfinite(f)) return (u16)0x5F80;  // diagnostic sentinel ~1.8e19
  u32 u = __float_as_uint(f);
  return (u16)((u + 0x7fffu + ((u >> 16) & 1u)) >> 16);
}
__device__ __forceinline__ float4 cvt4(ushort4 v) {
  return make_float4(bf2f(v.x), bf2f(v.y), bf2f(v.z), bf2f(v.w));
}
// fast gelu (tanh form, exp-based): max |err| vs erf-gelu ~3e-4
__device__ __forceinline__ float gelu_f(float x) {
  const float y = 0.7978845608f * x * (1.f + 0.044715f * x * x);
  const float e = __expf(-2.f * fabsf(y));
  const float th = __builtin_copysignf((1.f - e) / (1.f + e), y);
  return 0.5f * x * (1.f + th);
}

union U16x8 { uint4 u4; bf16x8 v; u16 s[8]; };

// ---------------- dtype detect: ln1_w[0] == 1.0. bf16 -> 0x3F80, fp32 low half -> 0x0000
__global__ void k_detect(const u16* __restrict__ p, u32* __restrict__ flag) {
  if (blockIdx.x == 0 && threadIdx.x == 0) *flag = (p[0] == (u16)0x3F80) ? 0u : 1u;
}

__device__ __forceinline__ float ldf(const void* p, int i, bool f32) {
  return f32 ? ((const float*)p)[i] : bf2f(((const u16*)p)[i]);
}

// ---------------- fused small-param convert -> fz[idx] (segments contiguous)
__global__ __launch_bounds__(256) void k_cvt_all(
    const void* p0, const void* p1, const void* p2, const void* p3,
    const void* p4, const void* p5, const void* p6, const void* p7,
    const void* p8, const void* p9, const void* p10, const void* p11,
    const void* p12, const void* p13, const void* p14, const void* p15,
    float* __restrict__ dst, const u32* __restrict__ fl)
{
  const int i = blockIdx.x * 256 + threadIdx.x;
  if (i >= 33576) return;
  const bool xf = (*fl != 0);
  const void* s; int o;
  if      (i < 2592)  { s = p0;  o = i; }
  else if (i < 7182)  { s = p1;  o = i - 2592; }
  else if (i < 9774)  { s = p2;  o = i - 7182; }
  else if (i < 14364) { s = p3;  o = i - 9774; }
  else if (i < 23580) { s = p4;  o = i - 14364; }
  else if (i < 32796) { s = p5;  o = i - 23580; }
  else if (i < 32802) { s = p6;  o = i - 32796; }
  else if (i < 32808) { s = p7;  o = i - 32802; }
  else if (i < 32904) { s = p8;  o = i - 32808; }
  else if (i < 33000) { s = p9;  o = i - 32904; }
  else if (i < 33096) { s = p10; o = i - 33000; }
  else if (i < 33192) { s = p11; o = i - 33096; }
  else if (i < 33288) { s = p12; o = i - 33192; }
  else if (i < 33384) { s = p13; o = i - 33288; }
  else if (i < 33480) { s = p14; o = i - 33384; }
  else                { s = p15; o = i - 33480; }
  dst[i] = ldf(s, o, xf);
}

// ---------------- fused weight prep -> wb[idx] bf16 (segments contiguous)
__global__ __launch_bounds__(256) void k_wprep_all(
    const void* q1, const void* i1, const void* o1,
    const void* q2, const void* i2, const void* o2,
    u16* __restrict__ wbuf, const u32* __restrict__ fl)
{
  const int idx = blockIdx.x * 256 + threadIdx.x;
  if (idx >= 215040) return;
  const bool xf = (*fl != 0);
  const void* s; int local, M, Kr, Kpad;
  if      (idx < 27648)  { s = q1; local = idx;          M = 288; Kr = 96;  Kpad = 96;  }
  else if (idx < 82944)  { s = i1; local = idx - 27648;  M = 510; Kr = 96;  Kpad = 96;  }
  else if (idx < 107520) { s = o1; local = idx - 82944;  M = 96;  Kr = 255; Kpad = 256; }
  else if (idx < 135168) { s = q2; local = idx - 107520; M = 288; Kr = 96;  Kpad = 96;  }
  else if (idx < 190464) { s = i2; local = idx - 135168; M = 510; Kr = 96;  Kpad = 96;  }
  else                   { s = o2; local = idx - 190464; M = 96;  Kr = 255; Kpad = 256; }
  const int m = local / Kpad, k = local - m * Kpad;
  u16 v = 0;
  if (m < M && k < Kr) v = f2bf(ldf(s, m * Kr + k, xf));
  wbuf[idx] = v;
}

// ---------------- LN (+optional f add), tiled 96ch x 64px -> TRANSPOSED xT [NPLANE][96] bf16
// grid (1024, 1, 2)
__global__ __launch_bounds__(256) void k_lnp(
    const void* __restrict__ x, const u32* __restrict__ xfl,
    const void* __restrict__ f, const u32* __restrict__ ffl,
    const float* __restrict__ lnw, const float* __restrict__ lnb,
    u16* __restrict__ xT)
{
  __shared__ float xin[96 * 64];
  __shared__ float fin[96 * 64];
  __shared__ float ps[256], pq[256];
  __shared__ float mu[64], rsd[64];
  const int tid = threadIdx.x;
  const int pix0 = blockIdx.x * 64;
  const int z = blockIdx.z;
  const size_t eb = (size_t)z * BELEMS;
  u16* xTo = xT + (size_t)z * BSTR;
  const bool xf = xfl && (*xfl != 0);
  const bool ff = ffl && (*ffl != 0);

#pragma unroll
  for (int i = 0; i < 6; ++i) {
    const int u = tid + i * 256;
    const int c = u >> 4, p4 = (u & 15) << 2;
    const size_t base = eb + (size_t)c * NPLANE + pix0 + p4;
    const float4 v = xf ? *(const float4*)((const float*)x + base)
                        : cvt4(*(const ushort4*)((const u16*)x + base));
    *(float4*)(xin + c * 64 + p4) = v;
    if (f) {
      const float4 fv = ff ? *(const float4*)((const float*)f + base)
                           : cvt4(*(const ushort4*)((const u16*)f + base));
      *(float4*)(fin + c * 64 + p4) = fv;
    }
  }
  __syncthreads();
  {
    const int p = tid & 63, qq = tid >> 6;
    float s = 0.f, q = 0.f;
    const int c0 = qq * 24;
#pragma unroll 8
    for (int c = c0; c < c0 + 24; ++c) {
      const float v = xin[c * 64 + p];
      s += v; q += v * v;
    }
    ps[tid] = s; pq[tid] = q;
  }
  __syncthreads();
  if (tid < 64) {
    const float s = ps[tid] + ps[tid + 64] + ps[tid + 128] + ps[tid + 192];
    const float q = pq[tid] + pq[tid + 64] + pq[tid + 128] + pq[tid + 192];
    const float m = s * (1.f / 96.f);
    mu[tid] = m;
    rsd[tid] = rsqrtf(fmaxf(q * (1.f / 96.f) - m * m, 0.f) + 1e-5f);
  }
  __syncthreads();
#pragma unroll
  for (int i = 0; i < 6; ++i) {
    const int u = tid + i * 256;
    const int c = u >> 4, p4 = (u & 15) << 2;
    const float4 v = *(const float4*)(xin + c * 64 + p4);
    const float w = lnw[c], b = lnb[c];
    float o0 = (v.x - mu[p4 + 0]) * rsd[p4 + 0] * w + b;
    float o1 = (v.y - mu[p4 + 1]) * rsd[p4 + 1] * w + b;
    float o2 = (v.z - mu[p4 + 2]) * rsd[p4 + 2] * w + b;
    float o3 = (v.w - mu[p4 + 3]) * rsd[p4 + 3] * w + b;
    if (f) {
      const float4 fv = *(const float4*)(fin + c * 64 + p4);
      o0 += fv.x; o1 += fv.y; o2 += fv.z; o3 += fv.w;
    }
    *(float4*)(xin + c * 64 + p4) = make_float4(o0, o1, o2, o3);
  }
  __syncthreads();
#pragma unroll
  for (int i = 0; i < 3; ++i) {
    const int u = tid + i * 256;
    const int px = u / 12, q = u - px * 12;
    U16x8 pk;
#pragma unroll
    for (int e = 0; e < 8; ++e) pk.s[e] = f2bf(xin[(q * 8 + e) * 64 + px]);
    *(uint4*)(xTo + (size_t)(pix0 + px) * 96 + q * 8) = pk.u4;
  }
}

// ---------------- MFMA GEMM (BT input, K=96 fixed): out[oc][n] bf16 planes
// grid (ceil(OC/96), 512, 2). LDS-staged coalesced epilogue.
__global__ __launch_bounds__(256) void k_gemm_bt(
    const u16* __restrict__ BT, size_t bts, const u16* __restrict__ A,
    int OC, u16* __restrict__ out, size_t ots)
{
  __shared__ u16 Bs[128 * 104];  // staging; epilogue reuses as ct[96][136]
  const int t = threadIdx.x;
  const int oc0 = blockIdx.x * 96;
  const int n0 = blockIdx.y * 128;
  const int z = blockIdx.z;
  const u16* BTz = BT + (size_t)z * bts;
  u16* outz = out + (size_t)z * ots;
  const int l = t & 63, wid = t >> 6, wm = wid >> 1, wn = wid & 1;

  const uint4* src = (const uint4*)(BTz + (size_t)n0 * 96);
#pragma unroll
  for (int i = 0; i < 6; ++i) {
    const int u = t + i * 256;
    const int r = u / 12, q = u - r * 12;
    *(uint4*)(Bs + r * 104 + q * 8) = src[u];
  }
  __syncthreads();

  f32x4 acc[3][4];
#pragma unroll
  for (int m = 0; m < 3; ++m)
#pragma unroll
    for (int n = 0; n < 4; ++n) acc[m][n] = (f32x4){0.f, 0.f, 0.f, 0.f};

#pragma unroll
  for (int ks = 0; ks < 3; ++ks) {
    const int kk = (ks << 5) + ((l >> 4) << 3);
    U16x8 a[3], b[4];
#pragma unroll
    for (int m = 0; m < 3; ++m)
      a[m].u4 = *(const uint4*)(A + (size_t)(oc0 + wm * 48 + m * 16 + (l & 15)) * 96 + kk);
#pragma unroll
    for (int ns = 0; ns < 4; ++ns)
      b[ns].u4 = *(const uint4*)(Bs + (wn * 64 + ns * 16 + (l & 15)) * 104 + kk);
#pragma unroll
    for (int m = 0; m < 3; ++m)
#pragma unroll
      for (int ns = 0; ns < 4; ++ns)
        acc[m][ns] = __builtin_amdgcn_mfma_f32_16x16x32_bf16(a[m].v, b[ns].v, acc[m][ns], 0, 0, 0);
  }

  __syncthreads();
  u16* ct = Bs;  // [96][136]
#pragma unroll
  for (int m = 0; m < 3; ++m) {
    const int rl = wm * 48 + m * 16 + ((l >> 4) << 2);
#pragma unroll
    for (int ns = 0; ns < 4; ++ns) {
      const int nl = wn * 64 + ns * 16 + (l & 15);
#pragma unroll
      for (int r = 0; r < 4; ++r) ct[(rl + r) * 136 + nl] = f2bf(acc[m][ns][r]);
    }
  }
  __syncthreads();
#pragma unroll
  for (int i = 0; i < 6; ++i) {
    const int u = t + i * 256;
    const int r = u >> 4, q = u & 15;
    if (oc0 + r < OC) {
      const uint4 pk = *(const uint4*)(ct + r * 136 + q * 8);
      *(uint4*)(outz + (size_t)(oc0 + r) * NPLANE + n0 + q * 8) = pk;
    }
  }
}

// ---------------- MFMA GEMM (plane-gather input): out[oc][n] = sum_k A[oc][k]*B[k][n] (+res)
// grid (1, 512, 2). B from planes [K][NPLANE] via scalar gather + XOR-swizzled LDS.
__global__ __launch_bounds__(256) void k_gemm(
    const u16* __restrict__ xsrc, size_t xzs, const u16* __restrict__ A, int azs,
    int K, int Kpad, int OC,
    const void* __restrict__ res, const u32* __restrict__ rfl,
    void* __restrict__ out, const u32* __restrict__ ofl)
{
  __shared__ uint4 Bt[128 * 16];
  const int t = threadIdx.x;
  const int p = t & 127, h = t >> 7;
  const int oc0 = blockIdx.x * 96;
  const int n0 = blockIdx.y * 128;
  const int z = blockIdx.z;
  const u16* xz = xsrc + (size_t)z * xzs;
  const u16* Az = A + (size_t)z * (size_t)azs;
  const size_t eb = (size_t)z * BELEMS;
  const int nglob = n0 + p;
  const int l = t & 63, wid = t >> 6, wm = wid >> 1, wn = wid & 1;

  f32x4 acc[3][4];
#pragma unroll
  for (int m = 0; m < 3; ++m)
#pragma unroll
    for (int n = 0; n < 4; ++n) acc[m][n] = (f32x4){0.f, 0.f, 0.f, 0.f};

  for (int kb = 0; kb < K; kb += 128) {
    if (kb) __syncthreads();
    const int kc = min(128, K - kb);
    const int U = (kc + 7) >> 3;
    const int uh = U >> 1;
    for (int j = 0; j < uh; ++j) {
      const int u = h * uh + j;
      const int cb = kb + u * 8;
      U16x8 pk;
#pragma unroll
      for (int e = 0; e < 8; ++e) {
        const int c = cb + e;
        pk.s[e] = (c < K) ? xz[(size_t)c * NPLANE + nglob] : (u16)0;
      }
      Bt[p * 16 + (u ^ (p & 7))] = pk.u4;
    }
    __syncthreads();
    const int nks = (kc + 31) >> 5;
    for (int ks = 0; ks < nks; ++ks) {
      U16x8 a[3], b[4];
      const int kk = kb + ks * 32 + ((l >> 4) << 3);
#pragma unroll
      for (int m = 0; m < 3; ++m) {
        const int row = oc0 + wm * 48 + m * 16 + (l & 15);
        a[m].u4 = ((const uint4*)Az)[((size_t)row * Kpad + kk) >> 3];
      }
#pragma unroll
      for (int ns = 0; ns < 4; ++ns) {
        const int row = wn * 64 + ns * 16 + (l & 15);
        const int up = (ks * 4 + (l >> 4)) ^ (row & 7);
        b[ns].u4 = Bt[row * 16 + up];
      }
#pragma unroll
      for (int m = 0; m < 3; ++m)
#pragma unroll
        for (int ns = 0; ns < 4; ++ns)
          acc[m][ns] = __builtin_amdgcn_mfma_f32_16x16x32_bf16(a[m].v, b[ns].v, acc[m][ns], 0, 0, 0);
    }
  }

  const bool rf = rfl && (*rfl != 0);
  const bool of = ofl && (*ofl != 0);
#pragma unroll
  for (int m = 0; m < 3; ++m) {
    const int ocb = oc0 + wm * 48 + m * 16 + ((l >> 4) << 2);
#pragma unroll
    for (int ns = 0; ns < 4; ++ns) {
      const int n = n0 + wn * 64 + ns * 16 + (l & 15);
#pragma unroll
      for (int r = 0; r < 4; ++r) {
        const int oc = ocb + r;
        if (oc < OC) {
          float v = acc[m][ns][r];
          const size_t gi = eb + (size_t)oc * NPLANE + n;
          if (res) v += rf ? ((const float*)res)[gi] : bf2f(((const u16*)res)[gi]);
          if (of) ((float*)out)[gi] = v;
          else    ((u16*)out)[gi] = f2bf(v);
        }
      }
    }
  }
}

// ---------------- depthwise 3x3 (zero pad 1). grid (16, 288, 2). 2 cols/thread, 8 rows,
// zero-padded LDS rows (264 w, +4 offset) -> all reads are aligned float2, conflict-free.
__global__ __launch_bounds__(256) void k_dw(
    const u16* __restrict__ in, const float* __restrict__ w9, u16* __restrict__ out)
{
  const int c = blockIdx.y;
  const int r0 = blockIdx.x * 16;
  const int z = blockIdx.z;
  __shared__ float tt[18 * 264];
  const int tid = threadIdx.x;
  const u16* ip = in + (size_t)z * ASTR + (size_t)c * NPLANE;
  if (tid < 144) {
    const int r = tid >> 3, e = tid & 7;
    tt[r * 264 + (e < 4 ? e : 256 + e)] = 0.f;
  }
  for (int u = tid; u < 1152; u += 256) {
    const int r = u >> 6, p4 = (u & 63) << 2;
    const int gr = r0 - 1 + r;
    float4 fv = make_float4(0.f, 0.f, 0.f, 0.f);
    if (gr >= 0 && gr < 256) fv = cvt4(*(const ushort4*)(ip + gr * 256 + p4));
    *(float4*)(tt + r * 264 + 4 + p4) = fv;
  }
  float wr[9];
#pragma unroll
  for (int i = 0; i < 9; ++i) wr[i] = w9[c * 9 + i];
  __syncthreads();
  const int cp = tid & 127, rh = tid >> 7;
  const int cl = cp << 1, rb = rh << 3;
  float a0, a1, a2, a3, b0, b1, b2, b3;
  {
    const float* p0 = tt + rb * 264 + cl;
    float2 L = *(const float2*)(p0 + 2), M = *(const float2*)(p0 + 4), R = *(const float2*)(p0 + 6);
    a0 = L.y; a1 = M.x; a2 = M.y; a3 = R.x;
    const float* p1 = tt + (rb + 1) * 264 + cl;
    L = *(const float2*)(p1 + 2); M = *(const float2*)(p1 + 4); R = *(const float2*)(p1 + 6);
    b0 = L.y; b1 = M.x; b2 = M.y; b3 = R.x;
  }
  u16* op = out + (size_t)z * BSTR + (size_t)c * NPLANE + (size_t)(r0 + rb) * 256 + cl;
#pragma unroll
  for (int rr = 0; rr < 8; ++rr) {
    const float* pc = tt + (rb + 2 + rr) * 264 + cl;
    const float2 L = *(const float2*)(pc + 2), M = *(const float2*)(pc + 4), R = *(const float2*)(pc + 6);
    const float c0 = L.y, c1 = M.x, c2 = M.y, c3 = R.x;
    const float o0 = wr[0] * a0 + wr[1] * a1 + wr[2] * a2
                   + wr[3] * b0 + wr[4] * b1 + wr[5] * b2
                   + wr[6] * c0 + wr[7] * c1 + wr[8] * c2;
    const float o1 = wr[0] * a1 + wr[1] * a2 + wr[2] * a3
                   + wr[3] * b1 + wr[4] * b2 + wr[5] * b3
                   + wr[6] * c1 + wr[7] * c2 + wr[8] * c3;
    *(u32*)(op + rr * 256) = (u32)f2bf(o0) | ((u32)f2bf(o1) << 16);
    a0 = b0; a1 = b1; a2 = b2; a3 = b3;
    b0 = c0; b1 = c1; b2 = c2; b3 = c3;
  }
}

// ---------------- depthwise 3x3 pair + fast-gelu(x1)*x2. grid (16, 255, 2). same layout.
__global__ __launch_bounds__(256) void k_dw_gelu(
    const u16* __restrict__ in, const float* __restrict__ w9, u16* __restrict__ out)
{
  const int c = blockIdx.y;
  const int r0 = blockIdx.x * 16;
  const int z = blockIdx.z;
  __shared__ float t1[18 * 264];
  __shared__ float t2[18 * 264];
  const int tid = threadIdx.x;
  const u16* ip1 = in + (size_t)z * ASTR + (size_t)c * NPLANE;
  const u16* ip2 = in + (size_t)z * ASTR + (size_t)(c + 255) * NPLANE;
  if (tid < 144) {
    const int r = tid >> 3, e = tid & 7;
    const int idx = r * 264 + (e < 4 ? e : 256 + e);
    t1[idx] = 0.f; t2[idx] = 0.f;
  }
  for (int u = tid; u < 1152; u += 256) {
    const int r = u >> 6, p4 = (u & 63) << 2;
    const int gr = r0 - 1 + r;
    float4 fa = make_float4(0.f, 0.f, 0.f, 0.f), fb = fa;
    if (gr >= 0 && gr < 256) {
      fa = cvt4(*(const ushort4*)(ip1 + gr * 256 + p4));
      fb = cvt4(*(const ushort4*)(ip2 + gr * 256 + p4));
    }
    *(float4*)(t1 + r * 264 + 4 + p4) = fa;
    *(float4*)(t2 + r * 264 + 4 + p4) = fb;
  }
  float wa[9], wb9[9];
#pragma unroll
  for (int i = 0; i < 9; ++i) { wa[i] = w9[c * 9 + i]; wb9[i] = w9[(c + 255) * 9 + i]; }
  __syncthreads();
  const int cp = tid & 127, rh = tid >> 7;
  const int cl = cp << 1, rb = rh << 3;
  float a0, a1, a2, a3, b0, b1, b2, b3;
  float d0, d1, d2, d3, e0, e1, e2, e3;
  {
    const float* p0 = t1 + rb * 264 + cl;
    float2 L = *(const float2*)(p0 + 2), M = *(const float2*)(p0 + 4), R = *(const float2*)(p0 + 6);
    a0 = L.y; a1 = M.x; a2 = M.y; a3 = R.x;
    const float* p1 = t1 + (rb + 1) * 264 + cl;
    L = *(const float2*)(p1 + 2); M = *(const float2*)(p1 + 4); R = *(const float2*)(p1 + 6);
    b0 = L.y; b1 = M.x; b2 = M.y; b3 = R.x;
    const float* q0 = t2 + rb * 264 + cl;
    L = *(const float2*)(q0 + 2); M = *(const float2*)(q0 + 4); R = *(const float2*)(q0 + 6);
    d0 = L.y; d1 = M.x; d2 = M.y; d3 = R.x;
    const float* q1 = t2 + (rb + 1) * 264 + cl;
    L = *(const float2*)(q1 + 2); M = *(const float2*)(q1 + 4); R = *(const float2*)(q1 + 6);
    e0 = L.y; e1 = M.x; e2 = M.y; e3 = R.x;
  }
  u16* op = out + (size_t)z * BSTR + (size_t)c * NPLANE + (size_t)(r0 + rb) * 256 + cl;
#pragma unroll
  for (int rr = 0; rr < 8; ++rr) {
    const float* pc = t1 + (rb + 2 + rr) * 264 + cl;
    float2 L = *(const float2*)(pc + 2), M = *(const float2*)(pc + 4), R = *(const float2*)(pc + 6);
    const float c0 = L.y, c1 = M.x, c2 = M.y, c3 = R.x;
    const float* qc = t2 + (rb + 2 + rr) * 264 + cl;
    L = *(const float2*)(qc + 2); M = *(const float2*)(qc + 4); R = *(const float2*)(qc + 6);
    const float f0 = L.y, f1 = M.x, f2 = M.y, f3 = R.x;
    const float g10 = wa[0] * a0 + wa[1] * a1 + wa[2] * a2
                    + wa[3] * b0 + wa[4] * b1 + wa[5] * b2
                    + wa[6] * c0 + wa[7] * c1 + wa[8] * c2;
    const float g11 = wa[0] * a1 + wa[1] * a2 + wa[2] * a3
                    + wa[3] * b1 + wa[4] * b2 + wa[5] * b3
                    + wa[6] * c1 + wa[7] * c2 + wa[8] * c3;
    const float g20 = wb9[0] * d0 + wb9[1] * d1 + wb9[2] * d2
                    + wb9[3] * e0 + wb9[4] * e1 + wb9[5] * e2
                    + wb9[6] * f0 + wb9[7] * f1 + wb9[8] * f2;
    const float g21 = wb9[0] * d1 + wb9[1] * d2 + wb9[2] * d3
                    + wb9[3] * e1 + wb9[4] * e2 + wb9[5] * e3
                    + wb9[6] * f1 + wb9[7] * f2 + wb9[8] * f3;
    const float o0 = gelu_f(g10) * g20;
    const float o1 = gelu_f(g11) * g21;
    *(u32*)(op + rr * 256) = (u32)f2bf(o0) | ((u32)f2bf(o1) << 16);
    a0 = b0; a1 = b1; a2 = b2; a3 = b3;
    b0 = c0; b1 = c1; b2 = c2; b3 = c3;
    d0 = e0; d1 = e1; d2 = e2; d3 = e3;
    e0 = f0; e1 = f1; e2 = f2; e3 = f3;
  }
}

// ---------------- MFMA Gram: G = [q;k]·[q;k]^T -> S quadrant + norms. grid (128, 6, 2).
__global__ __launch_bounds__(256) void k_reduce_s(
    const u16* __restrict__ qkv, float* __restrict__ S,
    float* __restrict__ qn2, float* __restrict__ kn2)
{
  const int h = blockIdx.y;
  const int n0 = blockIdx.x * 512;
  const int zb = blockIdx.z;
  const u16* qz = qkv + (size_t)zb * BSTR;
  float* Sz = S + zb * 1728;
  float* qn2z = qn2 + zb * 1728;
  float* kn2z = kn2 + zb * 1728;
  __shared__ uint4 st[64 * 33];
  const int tid = threadIdx.x;
  const int l = tid & 63, w = tid >> 6;

#pragma unroll
  for (int i = 0; i < 8; ++i) {
    const int idx = tid + i * 256;
    const int c = idx & 63, r = idx >> 6;
    const int plane = (r < 16) ? (h * 16 + r) : (96 + h * 16 + (r - 16));
    st[c * 33 + r] = *(const uint4*)(qz + (size_t)plane * NPLANE + n0 + c * 8);
  }
  __syncthreads();

  f32x16 acc;
#pragma unroll
  for (int j = 0; j < 16; ++j) acc[j] = 0.f;
  const int row = l & 31;
  const int cg = (w << 4) + (l >> 5);
#pragma unroll
  for (int s = 0; s < 8; ++s) {
    U16x8 frag;
    frag.u4 = st[(cg + s * 2) * 33 + row];
    acc = __builtin_amdgcn_mfma_f32_32x32x16_bf16(frag.v, frag.v, acc, 0, 0, 0);
  }
  __syncthreads();

  float* fs = (float*)st;
#pragma unroll
  for (int j = 0; j < 16; ++j) {
    const int rj = (j & 3) + 8 * (j >> 2) + 4 * (l >> 5);
    fs[w * 1024 + rj * 32 + (l & 31)] = acc[j];
  }
  __syncthreads();
#pragma unroll
  for (int e4 = 0; e4 < 4; ++e4) {
    const int e = tid * 4 + e4;
    const float v = fs[e] + fs[1024 + e] + fs[2048 + e] + fs[3072 + e];
    const int r = e >> 5, cc = e & 31;
    if (r < 16 && cc >= 16) atomicAdd(Sz + h * 256 + r * 16 + (cc - 16), v);
    if (r == cc) {
      if (r < 16) atomicAdd(qn2z + h * 16 + r, v);
      else        atomicAdd(kn2z + h * 16 + (r - 16), v);
    }
  }
}

// ---------------- softmax + fold proj -> Mtb bf16 [e][dg] (96x96). grid (1,1,2).
__global__ __launch_bounds__(256) void k_softmax_m(
    const float* __restrict__ S, const float* __restrict__ qn2, const float* __restrict__ kn2,
    const float* __restrict__ temp, const float* __restrict__ proj, u16* __restrict__ Mtb)
{
  __shared__ float attn[6 * 256];
  const int tid = threadIdx.x;
  const int zb = blockIdx.z;
  const float* Sz = S + zb * 1728;
  const float* qn2z = qn2 + zb * 1728;
  const float* kn2z = kn2 + zb * 1728;
  u16* Mz = Mtb + zb * 9216;
  if (tid < 96) {
    const int h = tid >> 4, i = tid & 15;
    const float qn = fmaxf(sqrtf(qn2z[tid]), 1e-12f);
    const float tp = temp[h];
    float row[16];
    float mx = -3.4e38f;
#pragma unroll
    for (int d = 0; d < 16; ++d) {
      const float kn = fmaxf(sqrtf(kn2z[h * 16 + d]), 1e-12f);
      row[d] = Sz[h * 256 + i * 16 + d] / (qn * kn) * tp;
      mx = fmaxf(mx, row[d]);
    }
    float sum = 0.f;
#pragma unroll
    for (int d = 0; d < 16; ++d) { row[d] = expf(row[d] - mx); sum += row[d]; }
    const float inv = 1.f / sum;
#pragma unroll
    for (int d = 0; d < 16; ++d) attn[h * 256 + i * 16 + d] = row[d] * inv;
  }
  __syncthreads();
  for (int u = tid; u < 9216; u += 256) {
    const int e = u / 96, dg = u - e * 96;
    const int h = dg >> 4, d = dg & 15;
    float s = 0.f;
#pragma unroll
    for (int i = 0; i < 16; ++i)
      s += proj[e * 96 + h * 16 + i] * attn[h * 256 + i * 16 + d];
    Mz[u] = f2bf(s);
  }
}

extern "C" void kernel_launch(void* const* d_in, const int* in_sizes, int n_in,
                              void* d_out, int out_size, void* d_ws, size_t ws_size,
                              hipStream_t stream)
{
  (void)in_sizes; (void)n_in; (void)out_size;
  if (ws_size < (size_t)234975000) return;  // diagnostic: too-small ws -> zero output

  const void* Fw  = d_in[0];
  const void* F0c = d_in[1];
  const void* Kdi = d_in[2];

  char* ws = (char*)d_ws;
  u16* xcur = (u16*)ws;                        // 2 x 96 planes bf16
  u16* bufA = (u16*)(ws + 25165824);           // 2 x 510 planes bf16
  u16* bufB = (u16*)(ws + 158859264);          // 2 x 288 planes bf16
  u16* wb   = (u16*)(ws + 234356736);          // weights 215040 + Mtb 2x9216
  u16* Wq1 = wb;           u16* Wi1 = wb + 27648;   u16* Wo1 = wb + 82944;
  u16* Wq2 = wb + 107520;  u16* Wi2 = wb + 135168;  u16* Wo2 = wb + 190464;
  u16* Mtb = wb + 215040;
  float* fz = (float*)(ws + 234823680);
  float* dwA1 = fz;          float* dwF1 = fz + 2592;
  float* dwA2 = fz + 7182;   float* dwF2 = fz + 9774;
  float* prj1 = fz + 14364;  float* prj2 = fz + 23580;
  float* tmp1 = fz + 32796;  float* tmp2 = fz + 32802;
  float* lnp  = fz + 32808;  // 8 x 96
  float* Sb   = fz + 33576;  // 2 x 1728 (S 1536 + Qn 96 + Kn 96 per batch)
  float* Qn   = Sb + 1536;
  float* Kn   = Sb + 1632;
  u32*  flag  = (u32*)(fz + 37032);

  k_detect<<<1, 64, 0, stream>>>((const u16*)d_in[3], flag);

  k_wprep_all<<<dim3(840), 256, 0, stream>>>(d_in[5], d_in[11], d_in[13],
                                             d_in[16], d_in[22], d_in[24], wb, flag);
  k_cvt_all<<<dim3(132), 256, 0, stream>>>(
      d_in[6], d_in[12], d_in[17], d_in[23], d_in[7], d_in[18], d_in[8], d_in[19],
      d_in[3], d_in[4], d_in[9], d_in[10], d_in[14], d_in[15], d_in[20], d_in[21],
      fz, flag);

  // attn: out = res + proj(attn(dw(conv(LN(x)+f))))  — both batches via grid.z
  auto attn_stage = [&](const void* x, const u32* xfl, const void* f, const u32* ffl,
                        const float* lw, const float* lb, const u16* Wq,
                        const float* dwf, const float* tmpf, const float* prjf,
                        const void* res, const u32* rfl,
                        void* outx, const u32* ofl) {
    hipMemsetAsync(Sb, 0, 2 * 1728 * sizeof(float), stream);
    k_lnp<<<dim3(1024, 1, 2), 256, 0, stream>>>(x, xfl, f, ffl, lw, lb, bufB);
    k_gemm_bt<<<dim3(3, 512, 2), 256, 0, stream>>>(bufB, BSTR, Wq, 288, bufA, ASTR);
    k_dw<<<dim3(16, 288, 2), 256, 0, stream>>>(bufA, dwf, bufB);
    k_reduce_s<<<dim3(128, 6, 2), 256, 0, stream>>>(bufB, Sb, Qn, Kn);
    k_softmax_m<<<dim3(1, 1, 2), 256, 0, stream>>>(Sb, Qn, Kn, tmpf, prjf, Mtb);
    k_gemm<<<dim3(1, 512, 2), 256, 0, stream>>>(bufB + (size_t)192 * NPLANE, BSTR,
                                                Mtb, 9216, 96, 96, 96,
                                                res, rfl, outx, ofl);
  };
  auto ffn_stage = [&](const void* x, const u32* xfl,
                       const float* lw, const float* lb, const u16* Wi,
                       const float* dwf, const u16* Wo,
                       void* outx, const u32* ofl) {
    k_lnp<<<dim3(1024, 1, 2), 256, 0, stream>>>(x, xfl, nullptr, nullptr, lw, lb, bufB);
    k_gemm_bt<<<dim3(6, 512, 2), 256, 0, stream>>>(bufB, BSTR, Wi, 510, bufA, ASTR);
    k_dw_gelu<<<dim3(16, 255, 2), 256, 0, stream>>>(bufA, dwf, bufB);
    k_gemm<<<dim3(1, 512, 2), 256, 0, stream>>>(bufB, BSTR, Wo, 0, 255, 256, 96,
                                                x, xfl, outx, ofl);
  };

  // stage 1: x1 = Fw + attn(LN1(Fw) + F0c)
  attn_stage(Fw, flag, F0c, flag, lnp + 0, lnp + 96, Wq1, dwA1, tmp1, prj1,
             Fw, flag, xcur, nullptr);
  // stage 2: x2 = x1 + ffn(LN2(x1))
  ffn_stage(xcur, nullptr, lnp + 192, lnp + 288, Wi1, dwF1, Wo1, xcur, nullptr);
  // stage 3: x3 = x2 + attn(LN3(x2) + Kd)
  attn_stage(xcur, nullptr, Kdi, flag, lnp + 384, lnp + 480, Wq2, dwA2, tmp2, prj2,
             xcur, nullptr, xcur, nullptr);
  // stage 4: out = x3 + ffn(LN4(x3))
  ffn_stage(xcur, nullptr, lnp + 576, lnp + 672, Wi2, dwF2, Wo2, d_out, flag);
}

// Round 17
// 736.691 us; speedup vs baseline: 1.0509x; 1.0509x over previous
//
#include <hip/hip_runtime.h>
#include <math.h>

using u16 = unsigned short;
using u32 = unsigned int;
typedef __attribute__((ext_vector_type(8))) short bf16x8;
typedef __attribute__((ext_vector_type(4))) float f32x4;
typedef __attribute__((ext_vector_type(16))) float f32x16;

#define NPLANE 65536
#define BELEMS ((size_t)6291456)     /* 96*65536 elements per batch */
#define ASTR   ((size_t)33423360)    /* bufA batch stride: 510*65536 u16 */
#define BSTR   ((size_t)18874368)    /* bufB batch stride: 288*65536 u16 */

__device__ __forceinline__ float bf2f(u16 u) { return __uint_as_float(((u32)u) << 16); }
__device__ __forceinline__ u16 f2bf(float f) {
  if (!__builtin_isfinite(f)) return (u16)0x5F80;  // diagnostic sentinel ~1.8e19
  u32 u = __float_as_uint(f);
  return (u16)((u + 0x7fffu + ((u >> 16) & 1u)) >> 16);
}
__device__ __forceinline__ float4 cvt4(ushort4 v) {
  return make_float4(bf2f(v.x), bf2f(v.y), bf2f(v.z), bf2f(v.w));
}
// fast gelu (tanh form, exp-based): max |err| vs erf-gelu ~3e-4
__device__ __forceinline__ float gelu_f(float x) {
  const float y = 0.7978845608f * x * (1.f + 0.044715f * x * x);
  const float e = __expf(-2.f * fabsf(y));
  const float th = __builtin_copysignf((1.f - e) / (1.f + e), y);
  return 0.5f * x * (1.f + th);
}

union U16x8 { uint4 u4; bf16x8 v; u16 s[8]; };

// ---------------- dtype detect: ln1_w[0] == 1.0. bf16 -> 0x3F80, fp32 low half -> 0x0000
__global__ void k_detect(const u16* __restrict__ p, u32* __restrict__ flag) {
  if (blockIdx.x == 0 && threadIdx.x == 0) *flag = (p[0] == (u16)0x3F80) ? 0u : 1u;
}

__device__ __forceinline__ float ldf(const void* p, int i, bool f32) {
  return f32 ? ((const float*)p)[i] : bf2f(((const u16*)p)[i]);
}

// ---------------- fused small-param convert -> fz[idx] (segments contiguous)
__global__ __launch_bounds__(256) void k_cvt_all(
    const void* p0, const void* p1, const void* p2, const void* p3,
    const void* p4, const void* p5, const void* p6, const void* p7,
    const void* p8, const void* p9, const void* p10, const void* p11,
    const void* p12, const void* p13, const void* p14, const void* p15,
    float* __restrict__ dst, const u32* __restrict__ fl)
{
  const int i = blockIdx.x * 256 + threadIdx.x;
  if (i >= 33576) return;
  const bool xf = (*fl != 0);
  const void* s; int o;
  if      (i < 2592)  { s = p0;  o = i; }
  else if (i < 7182)  { s = p1;  o = i - 2592; }
  else if (i < 9774)  { s = p2;  o = i - 7182; }
  else if (i < 14364) { s = p3;  o = i - 9774; }
  else if (i < 23580) { s = p4;  o = i - 14364; }
  else if (i < 32796) { s = p5;  o = i - 23580; }
  else if (i < 32802) { s = p6;  o = i - 32796; }
  else if (i < 32808) { s = p7;  o = i - 32802; }
  else if (i < 32904) { s = p8;  o = i - 32808; }
  else if (i < 33000) { s = p9;  o = i - 32904; }
  else if (i < 33096) { s = p10; o = i - 33000; }
  else if (i < 33192) { s = p11; o = i - 33096; }
  else if (i < 33288) { s = p12; o = i - 33192; }
  else if (i < 33384) { s = p13; o = i - 33288; }
  else if (i < 33480) { s = p14; o = i - 33384; }
  else                { s = p15; o = i - 33480; }
  dst[i] = ldf(s, o, xf);
}

// ---------------- fused weight prep -> wb[idx] bf16 (segments contiguous)
__global__ __launch_bounds__(256) void k_wprep_all(
    const void* q1, const void* i1, const void* o1,
    const void* q2, const void* i2, const void* o2,
    u16* __restrict__ wbuf, const u32* __restrict__ fl)
{
  const int idx = blockIdx.x * 256 + threadIdx.x;
  if (idx >= 215040) return;
  const bool xf = (*fl != 0);
  const void* s; int local, M, Kr, Kpad;
  if      (idx < 27648)  { s = q1; local = idx;          M = 288; Kr = 96;  Kpad = 96;  }
  else if (idx < 82944)  { s = i1; local = idx - 27648;  M = 510; Kr = 96;  Kpad = 96;  }
  else if (idx < 107520) { s = o1; local = idx - 82944;  M = 96;  Kr = 255; Kpad = 256; }
  else if (idx < 135168) { s = q2; local = idx - 107520; M = 288; Kr = 96;  Kpad = 96;  }
  else if (idx < 190464) { s = i2; local = idx - 135168; M = 510; Kr = 96;  Kpad = 96;  }
  else                   { s = o2; local = idx - 190464; M = 96;  Kr = 255; Kpad = 256; }
  const int m = local / Kpad, k = local - m * Kpad;
  u16 v = 0;
  if (m < M && k < Kr) v = f2bf(ldf(s, m * Kr + k, xf));
  wbuf[idx] = v;
}

// ---------------- LN (+optional f add), tiled 96ch x 64px -> TRANSPOSED xT [NPLANE][96] bf16
// grid (1024, 1, 2)
__global__ __launch_bounds__(256) void k_lnp(
    const void* __restrict__ x, const u32* __restrict__ xfl,
    const void* __restrict__ f, const u32* __restrict__ ffl,
    const float* __restrict__ lnw, const float* __restrict__ lnb,
    u16* __restrict__ xT)
{
  __shared__ float xin[96 * 64];
  __shared__ float fin[96 * 64];
  __shared__ float ps[256], pq[256];
  __shared__ float mu[64], rsd[64];
  const int tid = threadIdx.x;
  const int pix0 = blockIdx.x * 64;
  const int z = blockIdx.z;
  const size_t eb = (size_t)z * BELEMS;
  u16* xTo = xT + (size_t)z * BSTR;
  const bool xf = xfl && (*xfl != 0);
  const bool ff = ffl && (*ffl != 0);

#pragma unroll
  for (int i = 0; i < 6; ++i) {
    const int u = tid + i * 256;
    const int c = u >> 4, p4 = (u & 15) << 2;
    const size_t base = eb + (size_t)c * NPLANE + pix0 + p4;
    const float4 v = xf ? *(const float4*)((const float*)x + base)
                        : cvt4(*(const ushort4*)((const u16*)x + base));
    *(float4*)(xin + c * 64 + p4) = v;
    if (f) {
      const float4 fv = ff ? *(const float4*)((const float*)f + base)
                           : cvt4(*(const ushort4*)((const u16*)f + base));
      *(float4*)(fin + c * 64 + p4) = fv;
    }
  }
  __syncthreads();
  {
    const int p = tid & 63, qq = tid >> 6;
    float s = 0.f, q = 0.f;
    const int c0 = qq * 24;
#pragma unroll 8
    for (int c = c0; c < c0 + 24; ++c) {
      const float v = xin[c * 64 + p];
      s += v; q += v * v;
    }
    ps[tid] = s; pq[tid] = q;
  }
  __syncthreads();
  if (tid < 64) {
    const float s = ps[tid] + ps[tid + 64] + ps[tid + 128] + ps[tid + 192];
    const float q = pq[tid] + pq[tid + 64] + pq[tid + 128] + pq[tid + 192];
    const float m = s * (1.f / 96.f);
    mu[tid] = m;
    rsd[tid] = rsqrtf(fmaxf(q * (1.f / 96.f) - m * m, 0.f) + 1e-5f);
  }
  __syncthreads();
#pragma unroll
  for (int i = 0; i < 6; ++i) {
    const int u = tid + i * 256;
    const int c = u >> 4, p4 = (u & 15) << 2;
    const float4 v = *(const float4*)(xin + c * 64 + p4);
    const float w = lnw[c], b = lnb[c];
    float o0 = (v.x - mu[p4 + 0]) * rsd[p4 + 0] * w + b;
    float o1 = (v.y - mu[p4 + 1]) * rsd[p4 + 1] * w + b;
    float o2 = (v.z - mu[p4 + 2]) * rsd[p4 + 2] * w + b;
    float o3 = (v.w - mu[p4 + 3]) * rsd[p4 + 3] * w + b;
    if (f) {
      const float4 fv = *(const float4*)(fin + c * 64 + p4);
      o0 += fv.x; o1 += fv.y; o2 += fv.z; o3 += fv.w;
    }
    *(float4*)(xin + c * 64 + p4) = make_float4(o0, o1, o2, o3);
  }
  __syncthreads();
#pragma unroll
  for (int i = 0; i < 3; ++i) {
    const int u = tid + i * 256;
    const int px = u / 12, q = u - px * 12;
    U16x8 pk;
#pragma unroll
    for (int e = 0; e < 8; ++e) pk.s[e] = f2bf(xin[(q * 8 + e) * 64 + px]);
    *(uint4*)(xTo + (size_t)(pix0 + px) * 96 + q * 8) = pk.u4;
  }
}

// ---------------- MFMA GEMM (BT input, K=96 fixed): out[oc][n] bf16 planes
// grid (ceil(OC/96), 512, 2). LDS-staged coalesced epilogue.
__global__ __launch_bounds__(256) void k_gemm_bt(
    const u16* __restrict__ BT, size_t bts, const u16* __restrict__ A,
    int OC, u16* __restrict__ out, size_t ots)
{
  __shared__ u16 Bs[128 * 104];  // staging; epilogue reuses as ct[96][136]
  const int t = threadIdx.x;
  const int oc0 = blockIdx.x * 96;
  const int n0 = blockIdx.y * 128;
  const int z = blockIdx.z;
  const u16* BTz = BT + (size_t)z * bts;
  u16* outz = out + (size_t)z * ots;
  const int l = t & 63, wid = t >> 6, wm = wid >> 1, wn = wid & 1;

  const uint4* src = (const uint4*)(BTz + (size_t)n0 * 96);
#pragma unroll
  for (int i = 0; i < 6; ++i) {
    const int u = t + i * 256;
    const int r = u / 12, q = u - r * 12;
    *(uint4*)(Bs + r * 104 + q * 8) = src[u];
  }
  __syncthreads();

  f32x4 acc[3][4];
#pragma unroll
  for (int m = 0; m < 3; ++m)
#pragma unroll
    for (int n = 0; n < 4; ++n) acc[m][n] = (f32x4){0.f, 0.f, 0.f, 0.f};

#pragma unroll
  for (int ks = 0; ks < 3; ++ks) {
    const int kk = (ks << 5) + ((l >> 4) << 3);
    U16x8 a[3], b[4];
#pragma unroll
    for (int m = 0; m < 3; ++m)
      a[m].u4 = *(const uint4*)(A + (size_t)(oc0 + wm * 48 + m * 16 + (l & 15)) * 96 + kk);
#pragma unroll
    for (int ns = 0; ns < 4; ++ns)
      b[ns].u4 = *(const uint4*)(Bs + (wn * 64 + ns * 16 + (l & 15)) * 104 + kk);
#pragma unroll
    for (int m = 0; m < 3; ++m)
#pragma unroll
      for (int ns = 0; ns < 4; ++ns)
        acc[m][ns] = __builtin_amdgcn_mfma_f32_16x16x32_bf16(a[m].v, b[ns].v, acc[m][ns], 0, 0, 0);
  }

  __syncthreads();
  u16* ct = Bs;  // [96][136]
#pragma unroll
  for (int m = 0; m < 3; ++m) {
    const int rl = wm * 48 + m * 16 + ((l >> 4) << 2);
#pragma unroll
    for (int ns = 0; ns < 4; ++ns) {
      const int nl = wn * 64 + ns * 16 + (l & 15);
#pragma unroll
      for (int r = 0; r < 4; ++r) ct[(rl + r) * 136 + nl] = f2bf(acc[m][ns][r]);
    }
  }
  __syncthreads();
#pragma unroll
  for (int i = 0; i < 6; ++i) {
    const int u = t + i * 256;
    const int r = u >> 4, q = u & 15;
    if (oc0 + r < OC) {
      const uint4 pk = *(const uint4*)(ct + r * 136 + q * 8);
      *(uint4*)(outz + (size_t)(oc0 + r) * NPLANE + n0 + q * 8) = pk;
    }
  }
}

// ---------------- MFMA GEMM (plane-gather input): out[oc][n] = sum_k A[oc][k]*B[k][n] (+res)
// grid (1, 512, 2). B from planes [K][NPLANE] via scalar gather + XOR-swizzled LDS.
__global__ __launch_bounds__(256) void k_gemm(
    const u16* __restrict__ xsrc, size_t xzs, const u16* __restrict__ A, int azs,
    int K, int Kpad, int OC,
    const void* __restrict__ res, const u32* __restrict__ rfl,
    void* __restrict__ out, const u32* __restrict__ ofl)
{
  __shared__ uint4 Bt[128 * 16];
  const int t = threadIdx.x;
  const int p = t & 127, h = t >> 7;
  const int oc0 = blockIdx.x * 96;
  const int n0 = blockIdx.y * 128;
  const int z = blockIdx.z;
  const u16* xz = xsrc + (size_t)z * xzs;
  const u16* Az = A + (size_t)z * (size_t)azs;
  const size_t eb = (size_t)z * BELEMS;
  const int nglob = n0 + p;
  const int l = t & 63, wid = t >> 6, wm = wid >> 1, wn = wid & 1;

  f32x4 acc[3][4];
#pragma unroll
  for (int m = 0; m < 3; ++m)
#pragma unroll
    for (int n = 0; n < 4; ++n) acc[m][n] = (f32x4){0.f, 0.f, 0.f, 0.f};

  for (int kb = 0; kb < K; kb += 128) {
    if (kb) __syncthreads();
    const int kc = min(128, K - kb);
    const int U = (kc + 7) >> 3;
    const int uh = U >> 1;
    for (int j = 0; j < uh; ++j) {
      const int u = h * uh + j;
      const int cb = kb + u * 8;
      U16x8 pk;
#pragma unroll
      for (int e = 0; e < 8; ++e) {
        const int c = cb + e;
        pk.s[e] = (c < K) ? xz[(size_t)c * NPLANE + nglob] : (u16)0;
      }
      Bt[p * 16 + (u ^ (p & 7))] = pk.u4;
    }
    __syncthreads();
    const int nks = (kc + 31) >> 5;
    for (int ks = 0; ks < nks; ++ks) {
      U16x8 a[3], b[4];
      const int kk = kb + ks * 32 + ((l >> 4) << 3);
#pragma unroll
      for (int m = 0; m < 3; ++m) {
        const int row = oc0 + wm * 48 + m * 16 + (l & 15);
        a[m].u4 = ((const uint4*)Az)[((size_t)row * Kpad + kk) >> 3];
      }
#pragma unroll
      for (int ns = 0; ns < 4; ++ns) {
        const int row = wn * 64 + ns * 16 + (l & 15);
        const int up = (ks * 4 + (l >> 4)) ^ (row & 7);
        b[ns].u4 = Bt[row * 16 + up];
      }
#pragma unroll
      for (int m = 0; m < 3; ++m)
#pragma unroll
        for (int ns = 0; ns < 4; ++ns)
          acc[m][ns] = __builtin_amdgcn_mfma_f32_16x16x32_bf16(a[m].v, b[ns].v, acc[m][ns], 0, 0, 0);
    }
  }

  const bool rf = rfl && (*rfl != 0);
  const bool of = ofl && (*ofl != 0);
#pragma unroll
  for (int m = 0; m < 3; ++m) {
    const int ocb = oc0 + wm * 48 + m * 16 + ((l >> 4) << 2);
#pragma unroll
    for (int ns = 0; ns < 4; ++ns) {
      const int n = n0 + wn * 64 + ns * 16 + (l & 15);
#pragma unroll
      for (int r = 0; r < 4; ++r) {
        const int oc = ocb + r;
        if (oc < OC) {
          float v = acc[m][ns][r];
          const size_t gi = eb + (size_t)oc * NPLANE + n;
          if (res) v += rf ? ((const float*)res)[gi] : bf2f(((const u16*)res)[gi]);
          if (of) ((float*)out)[gi] = v;
          else    ((u16*)out)[gi] = f2bf(v);
        }
      }
    }
  }
}

// ---------------- depthwise 3x3 (zero pad 1). grid (16, 288, 2). 2 cols/thread, rows split.
__global__ __launch_bounds__(256) void k_dw(
    const u16* __restrict__ in, const float* __restrict__ w9, u16* __restrict__ out)
{
  const int c = blockIdx.y;
  const int r0 = blockIdx.x * 16;
  const int z = blockIdx.z;
  __shared__ float tt[18 * 256];
  const int tid = threadIdx.x;
  const u16* ip = in + (size_t)z * ASTR + (size_t)c * NPLANE;
  for (int u = tid; u < 1152; u += 256) {
    const int r = u >> 6, p4 = (u & 63) << 2;
    const int gr = r0 - 1 + r;
    float4 fv = make_float4(0.f, 0.f, 0.f, 0.f);
    if (gr >= 0 && gr < 256) fv = cvt4(*(const ushort4*)(ip + gr * 256 + p4));
    *(float4*)(tt + r * 256 + p4) = fv;
  }
  float wr[9];
#pragma unroll
  for (int i = 0; i < 9; ++i) wr[i] = w9[c * 9 + i];
  __syncthreads();
  const int cp = tid & 127, rh = tid >> 7;
  const int cl = cp << 1;
  const bool cm = cp > 0, cpk = cp < 127;
  const int rb = rh << 3;  // tile row base
  float a0 = cm ? tt[rb * 256 + cl - 1] : 0.f;
  float a1 = tt[rb * 256 + cl], a2 = tt[rb * 256 + cl + 1];
  float a3 = cpk ? tt[rb * 256 + cl + 2] : 0.f;
  float b0 = cm ? tt[(rb + 1) * 256 + cl - 1] : 0.f;
  float b1 = tt[(rb + 1) * 256 + cl], b2 = tt[(rb + 1) * 256 + cl + 1];
  float b3 = cpk ? tt[(rb + 1) * 256 + cl + 2] : 0.f;
  u16* op = out + (size_t)z * BSTR + (size_t)c * NPLANE + (size_t)(r0 + rb) * 256 + cl;
#pragma unroll
  for (int rr = 0; rr < 8; ++rr) {
    const int rn = (rb + 2 + rr) * 256;
    const float c0 = cm ? tt[rn + cl - 1] : 0.f;
    const float c1 = tt[rn + cl], c2 = tt[rn + cl + 1];
    const float c3 = cpk ? tt[rn + cl + 2] : 0.f;
    const float o0 = wr[0] * a0 + wr[1] * a1 + wr[2] * a2
                   + wr[3] * b0 + wr[4] * b1 + wr[5] * b2
                   + wr[6] * c0 + wr[7] * c1 + wr[8] * c2;
    const float o1 = wr[0] * a1 + wr[1] * a2 + wr[2] * a3
                   + wr[3] * b1 + wr[4] * b2 + wr[5] * b3
                   + wr[6] * c1 + wr[7] * c2 + wr[8] * c3;
    *(u32*)(op + rr * 256) = (u32)f2bf(o0) | ((u32)f2bf(o1) << 16);
    a0 = b0; a1 = b1; a2 = b2; a3 = b3;
    b0 = c0; b1 = c1; b2 = c2; b3 = c3;
  }
}

// ---------------- depthwise 3x3 pair + gelu(x1)*x2. grid (16, 255, 2). 2 cols/thread.
__global__ __launch_bounds__(256) void k_dw_gelu(
    const u16* __restrict__ in, const float* __restrict__ w9, u16* __restrict__ out)
{
  const int c = blockIdx.y;
  const int r0 = blockIdx.x * 16;
  const int z = blockIdx.z;
  __shared__ float t1[18 * 256];
  __shared__ float t2[18 * 256];
  const int tid = threadIdx.x;
  const u16* ip1 = in + (size_t)z * ASTR + (size_t)c * NPLANE;
  const u16* ip2 = in + (size_t)z * ASTR + (size_t)(c + 255) * NPLANE;
  for (int u = tid; u < 1152; u += 256) {
    const int r = u >> 6, p4 = (u & 63) << 2;
    const int gr = r0 - 1 + r;
    float4 fa = make_float4(0.f, 0.f, 0.f, 0.f), fb = fa;
    if (gr >= 0 && gr < 256) {
      fa = cvt4(*(const ushort4*)(ip1 + gr * 256 + p4));
      fb = cvt4(*(const ushort4*)(ip2 + gr * 256 + p4));
    }
    *(float4*)(t1 + r * 256 + p4) = fa;
    *(float4*)(t2 + r * 256 + p4) = fb;
  }
  float wa[9], wb[9];
#pragma unroll
  for (int i = 0; i < 9; ++i) { wa[i] = w9[c * 9 + i]; wb[i] = w9[(c + 255) * 9 + i]; }
  __syncthreads();
  const int cp = tid & 127, rh = tid >> 7;
  const int cl = cp << 1;
  const bool cm = cp > 0, cpk = cp < 127;
  const int rb = rh << 3;
  float a0 = cm ? t1[rb * 256 + cl - 1] : 0.f;
  float a1 = t1[rb * 256 + cl], a2 = t1[rb * 256 + cl + 1];
  float a3 = cpk ? t1[rb * 256 + cl + 2] : 0.f;
  float b0 = cm ? t1[(rb + 1) * 256 + cl - 1] : 0.f;
  float b1 = t1[(rb + 1) * 256 + cl], b2 = t1[(rb + 1) * 256 + cl + 1];
  float b3 = cpk ? t1[(rb + 1) * 256 + cl + 2] : 0.f;
  float d0 = cm ? t2[rb * 256 + cl - 1] : 0.f;
  float d1 = t2[rb * 256 + cl], d2 = t2[rb * 256 + cl + 1];
  float d3 = cpk ? t2[rb * 256 + cl + 2] : 0.f;
  float e0 = cm ? t2[(rb + 1) * 256 + cl - 1] : 0.f;
  float e1 = t2[(rb + 1) * 256 + cl], e2 = t2[(rb + 1) * 256 + cl + 1];
  float e3 = cpk ? t2[(rb + 1) * 256 + cl + 2] : 0.f;
  u16* op = out + (size_t)z * BSTR + (size_t)c * NPLANE + (size_t)(r0 + rb) * 256 + cl;
#pragma unroll
  for (int rr = 0; rr < 8; ++rr) {
    const int rn = (rb + 2 + rr) * 256;
    const float c0 = cm ? t1[rn + cl - 1] : 0.f;
    const float c1 = t1[rn + cl], c2 = t1[rn + cl + 1];
    const float c3 = cpk ? t1[rn + cl + 2] : 0.f;
    const float f0 = cm ? t2[rn + cl - 1] : 0.f;
    const float f1 = t2[rn + cl], f2 = t2[rn + cl + 1];
    const float f3 = cpk ? t2[rn + cl + 2] : 0.f;
    const float g10 = wa[0] * a0 + wa[1] * a1 + wa[2] * a2
                    + wa[3] * b0 + wa[4] * b1 + wa[5] * b2
                    + wa[6] * c0 + wa[7] * c1 + wa[8] * c2;
    const float g11 = wa[0] * a1 + wa[1] * a2 + wa[2] * a3
                    + wa[3] * b1 + wa[4] * b2 + wa[5] * b3
                    + wa[6] * c1 + wa[7] * c2 + wa[8] * c3;
    const float g20 = wb[0] * d0 + wb[1] * d1 + wb[2] * d2
                    + wb[3] * e0 + wb[4] * e1 + wb[5] * e2
                    + wb[6] * f0 + wb[7] * f1 + wb[8] * f2;
    const float g21 = wb[0] * d1 + wb[1] * d2 + wb[2] * d3
                    + wb[3] * e1 + wb[4] * e2 + wb[5] * e3
                    + wb[6] * f1 + wb[7] * f2 + wb[8] * f3;
    const float o0 = gelu_f(g10) * g20;
    const float o1 = gelu_f(g11) * g21;
    *(u32*)(op + rr * 256) = (u32)f2bf(o0) | ((u32)f2bf(o1) << 16);
    a0 = b0; a1 = b1; a2 = b2; a3 = b3;
    b0 = c0; b1 = c1; b2 = c2; b3 = c3;
    d0 = e0; d1 = e1; d2 = e2; d3 = e3;
    e0 = f0; e1 = f1; e2 = f2; e3 = f3;
  }
}

// ---------------- MFMA Gram: G = [q;k]·[q;k]^T -> S quadrant + norms. grid (128, 6, 2).
__global__ __launch_bounds__(256) void k_reduce_s(
    const u16* __restrict__ qkv, float* __restrict__ S,
    float* __restrict__ qn2, float* __restrict__ kn2)
{
  const int h = blockIdx.y;
  const int n0 = blockIdx.x * 512;
  const int zb = blockIdx.z;
  const u16* qz = qkv + (size_t)zb * BSTR;
  float* Sz = S + zb * 1728;
  float* qn2z = qn2 + zb * 1728;
  float* kn2z = kn2 + zb * 1728;
  __shared__ uint4 st[64 * 33];
  const int tid = threadIdx.x;
  const int l = tid & 63, w = tid >> 6;

#pragma unroll
  for (int i = 0; i < 8; ++i) {
    const int idx = tid + i * 256;
    const int c = idx & 63, r = idx >> 6;
    const int plane = (r < 16) ? (h * 16 + r) : (96 + h * 16 + (r - 16));
    st[c * 33 + r] = *(const uint4*)(qz + (size_t)plane * NPLANE + n0 + c * 8);
  }
  __syncthreads();

  f32x16 acc;
#pragma unroll
  for (int j = 0; j < 16; ++j) acc[j] = 0.f;
  const int row = l & 31;
  const int cg = (w << 4) + (l >> 5);
#pragma unroll
  for (int s = 0; s < 8; ++s) {
    U16x8 frag;
    frag.u4 = st[(cg + s * 2) * 33 + row];
    acc = __builtin_amdgcn_mfma_f32_32x32x16_bf16(frag.v, frag.v, acc, 0, 0, 0);
  }
  __syncthreads();

  float* fs = (float*)st;
#pragma unroll
  for (int j = 0; j < 16; ++j) {
    const int rj = (j & 3) + 8 * (j >> 2) + 4 * (l >> 5);
    fs[w * 1024 + rj * 32 + (l & 31)] = acc[j];
  }
  __syncthreads();
#pragma unroll
  for (int e4 = 0; e4 < 4; ++e4) {
    const int e = tid * 4 + e4;
    const float v = fs[e] + fs[1024 + e] + fs[2048 + e] + fs[3072 + e];
    const int r = e >> 5, cc = e & 31;
    if (r < 16 && cc >= 16) atomicAdd(Sz + h * 256 + r * 16 + (cc - 16), v);
    if (r == cc) {
      if (r < 16) atomicAdd(qn2z + h * 16 + r, v);
      else        atomicAdd(kn2z + h * 16 + (r - 16), v);
    }
  }
}

// ---------------- softmax + fold proj -> Mtb bf16 [e][dg] (96x96). grid (1,1,2).
__global__ __launch_bounds__(256) void k_softmax_m(
    const float* __restrict__ S, const float* __restrict__ qn2, const float* __restrict__ kn2,
    const float* __restrict__ temp, const float* __restrict__ proj, u16* __restrict__ Mtb)
{
  __shared__ float attn[6 * 256];
  const int tid = threadIdx.x;
  const int zb = blockIdx.z;
  const float* Sz = S + zb * 1728;
  const float* qn2z = qn2 + zb * 1728;
  const float* kn2z = kn2 + zb * 1728;
  u16* Mz = Mtb + zb * 9216;
  if (tid < 96) {
    const int h = tid >> 4, i = tid & 15;
    const float qn = fmaxf(sqrtf(qn2z[tid]), 1e-12f);
    const float tp = temp[h];
    float row[16];
    float mx = -3.4e38f;
#pragma unroll
    for (int d = 0; d < 16; ++d) {
      const float kn = fmaxf(sqrtf(kn2z[h * 16 + d]), 1e-12f);
      row[d] = Sz[h * 256 + i * 16 + d] / (qn * kn) * tp;
      mx = fmaxf(mx, row[d]);
    }
    float sum = 0.f;
#pragma unroll
    for (int d = 0; d < 16; ++d) { row[d] = expf(row[d] - mx); sum += row[d]; }
    const float inv = 1.f / sum;
#pragma unroll
    for (int d = 0; d < 16; ++d) attn[h * 256 + i * 16 + d] = row[d] * inv;
  }
  __syncthreads();
  for (int u = tid; u < 9216; u += 256) {
    const int e = u / 96, dg = u - e * 96;
    const int h = dg >> 4, d = dg & 15;
    float s = 0.f;
#pragma unroll
    for (int i = 0; i < 16; ++i)
      s += proj[e * 96 + h * 16 + i] * attn[h * 256 + i * 16 + d];
    Mz[u] = f2bf(s);
  }
}

extern "C" void kernel_launch(void* const* d_in, const int* in_sizes, int n_in,
                              void* d_out, int out_size, void* d_ws, size_t ws_size,
                              hipStream_t stream)
{
  (void)in_sizes; (void)n_in; (void)out_size;
  if (ws_size < (size_t)234975000) return;  // diagnostic: too-small ws -> zero output

  const void* Fw  = d_in[0];
  const void* F0c = d_in[1];
  const void* Kdi = d_in[2];

  char* ws = (char*)d_ws;
  u16* xcur = (u16*)ws;                        // 2 x 96 planes bf16
  u16* bufA = (u16*)(ws + 25165824);           // 2 x 510 planes bf16
  u16* bufB = (u16*)(ws + 158859264);          // 2 x 288 planes bf16
  u16* wb   = (u16*)(ws + 234356736);          // weights 215040 + Mtb 2x9216
  u16* Wq1 = wb;           u16* Wi1 = wb + 27648;   u16* Wo1 = wb + 82944;
  u16* Wq2 = wb + 107520;  u16* Wi2 = wb + 135168;  u16* Wo2 = wb + 190464;
  u16* Mtb = wb + 215040;
  float* fz = (float*)(ws + 234823680);
  float* dwA1 = fz;          float* dwF1 = fz + 2592;
  float* dwA2 = fz + 7182;   float* dwF2 = fz + 9774;
  float* prj1 = fz + 14364;  float* prj2 = fz + 23580;
  float* tmp1 = fz + 32796;  float* tmp2 = fz + 32802;
  float* lnp  = fz + 32808;  // 8 x 96
  float* Sb   = fz + 33576;  // 2 x 1728 (S 1536 + Qn 96 + Kn 96 per batch)
  float* Qn   = Sb + 1536;
  float* Kn   = Sb + 1632;
  u32*  flag  = (u32*)(fz + 37032);

  k_detect<<<1, 64, 0, stream>>>((const u16*)d_in[3], flag);

  k_wprep_all<<<dim3(840), 256, 0, stream>>>(d_in[5], d_in[11], d_in[13],
                                             d_in[16], d_in[22], d_in[24], wb, flag);
  k_cvt_all<<<dim3(132), 256, 0, stream>>>(
      d_in[6], d_in[12], d_in[17], d_in[23], d_in[7], d_in[18], d_in[8], d_in[19],
      d_in[3], d_in[4], d_in[9], d_in[10], d_in[14], d_in[15], d_in[20], d_in[21],
      fz, flag);

  // attn: out = res + proj(attn(dw(conv(LN(x)+f))))  — both batches via grid.z
  auto attn_stage = [&](const void* x, const u32* xfl, const void* f, const u32* ffl,
                        const float* lw, const float* lb, const u16* Wq,
                        const float* dwf, const float* tmpf, const float* prjf,
                        const void* res, const u32* rfl,
                        void* outx, const u32* ofl) {
    hipMemsetAsync(Sb, 0, 2 * 1728 * sizeof(float), stream);
    k_lnp<<<dim3(1024, 1, 2), 256, 0, stream>>>(x, xfl, f, ffl, lw, lb, bufB);
    k_gemm_bt<<<dim3(3, 512, 2), 256, 0, stream>>>(bufB, BSTR, Wq, 288, bufA, ASTR);
    k_dw<<<dim3(16, 288, 2), 256, 0, stream>>>(bufA, dwf, bufB);
    k_reduce_s<<<dim3(128, 6, 2), 256, 0, stream>>>(bufB, Sb, Qn, Kn);
    k_softmax_m<<<dim3(1, 1, 2), 256, 0, stream>>>(Sb, Qn, Kn, tmpf, prjf, Mtb);
    k_gemm<<<dim3(1, 512, 2), 256, 0, stream>>>(bufB + (size_t)192 * NPLANE, BSTR,
                                                Mtb, 9216, 96, 96, 96,
                                                res, rfl, outx, ofl);
  };
  auto ffn_stage = [&](const void* x, const u32* xfl,
                       const float* lw, const float* lb, const u16* Wi,
                       const float* dwf, const u16* Wo,
                       void* outx, const u32* ofl) {
    k_lnp<<<dim3(1024, 1, 2), 256, 0, stream>>>(x, xfl, nullptr, nullptr, lw, lb, bufB);
    k_gemm_bt<<<dim3(6, 512, 2), 256, 0, stream>>>(bufB, BSTR, Wi, 510, bufA, ASTR);
    k_dw_gelu<<<dim3(16, 255, 2), 256, 0, stream>>>(bufA, dwf, bufB);
    k_gemm<<<dim3(1, 512, 2), 256, 0, stream>>>(bufB, BSTR, Wo, 0, 255, 256, 96,
                                                x, xfl, outx, ofl);
  };

  // stage 1: x1 = Fw + attn(LN1(Fw) + F0c)
  attn_stage(Fw, flag, F0c, flag, lnp + 0, lnp + 96, Wq1, dwA1, tmp1, prj1,
             Fw, flag, xcur, nullptr);
  // stage 2: x2 = x1 + ffn(LN2(x1))
  ffn_stage(xcur, nullptr, lnp + 192, lnp + 288, Wi1, dwF1, Wo1, xcur, nullptr);
  // stage 3: x3 = x2 + attn(LN3(x2) + Kd)
  attn_stage(xcur, nullptr, Kdi, flag, lnp + 384, lnp + 480, Wq2, dwA2, tmp2, prj2,
             xcur, nullptr, xcur, nullptr);
  // stage 4: out = x3 + ffn(LN4(x3))
  ffn_stage(xcur, nullptr, lnp + 576, lnp + 672, Wi2, dwF2, Wo2, d_out, flag);
}